// Round 8
// baseline (7491.373 us; speedup 1.0000x reference)
//
#include <hip/hip_runtime.h>

// Problem constants (DeepCAD_1958505087412)
#define BB   8
#define NN   512      // nodes == timesteps
#define NDIM 128
#define HDIM 256      // GNN out dim == LSTM hidden
#define TT   512

__device__ __forceinline__ float sigmoidf_(float x) { return 1.0f / (1.0f + __expf(-x)); }
__device__ __forceinline__ float tanhf_(float x) { float e = __expf(2.0f * x); return 1.0f - 2.0f / (e + 1.0f); }

typedef _Float16 half2v __attribute__((ext_vector_type(2)));
typedef unsigned int uint4v __attribute__((ext_vector_type(4)));
__device__ __forceinline__ float fdot2_(unsigned int w, unsigned int h, float acc) {
    return __builtin_amdgcn_fdot2(__builtin_bit_cast(half2v, w),
                                  __builtin_bit_cast(half2v, h), acc, false);
}

// ---------------------------------------------------------------------------
// Y = X @ W^T + bias (optional ReLU). X:(M,K) W:(Nn,K) Y:(M,Nn) row-major.
// ---------------------------------------------------------------------------
template<int RELU>
__global__ __launch_bounds__(256) void gemm_nt(const float* __restrict__ X,
    const float* __restrict__ W, const float* __restrict__ bias,
    float* __restrict__ Y, int M, int K, int Nn)
{
    __shared__ float Xs[16][68];
    __shared__ float Ws[16][68];
    const int tid = threadIdx.x;
    const int m0 = blockIdx.y << 6;
    const int n0 = blockIdx.x << 6;
    const int lr = tid >> 2;           // 0..63
    const int lc = (tid & 3) << 2;     // 0,4,8,12
    const int tm = (tid >> 4) << 2;    // 0..60
    const int tn = (tid & 15) << 2;    // 0..60

    float acc[4][4] = {{0.f,0.f,0.f,0.f},{0.f,0.f,0.f,0.f},{0.f,0.f,0.f,0.f},{0.f,0.f,0.f,0.f}};

    const float* Xp = X + (size_t)(m0 + lr) * K + lc;
    const bool wok = (n0 + lr) < Nn;
    const float* Wp = wok ? (W + (size_t)(n0 + lr) * K + lc) : W;

    for (int k0 = 0; k0 < K; k0 += 16) {
        float4 xv = *(const float4*)(Xp + k0);
        float4 wv = *(const float4*)(Wp + k0);
        if (!wok) wv = make_float4(0.f, 0.f, 0.f, 0.f);
        __syncthreads();
        Xs[lc+0][lr]=xv.x; Xs[lc+1][lr]=xv.y; Xs[lc+2][lr]=xv.z; Xs[lc+3][lr]=xv.w;
        Ws[lc+0][lr]=wv.x; Ws[lc+1][lr]=wv.y; Ws[lc+2][lr]=wv.z; Ws[lc+3][lr]=wv.w;
        __syncthreads();
        #pragma unroll
        for (int kk = 0; kk < 16; ++kk) {
            const float4 a = *(const float4*)(&Xs[kk][tm]);
            const float4 b = *(const float4*)(&Ws[kk][tn]);
            acc[0][0] += a.x*b.x; acc[0][1] += a.x*b.y; acc[0][2] += a.x*b.z; acc[0][3] += a.x*b.w;
            acc[1][0] += a.y*b.x; acc[1][1] += a.y*b.y; acc[1][2] += a.y*b.z; acc[1][3] += a.y*b.w;
            acc[2][0] += a.z*b.x; acc[2][1] += a.z*b.y; acc[2][2] += a.z*b.z; acc[2][3] += a.z*b.w;
            acc[3][0] += a.w*b.x; acc[3][1] += a.w*b.y; acc[3][2] += a.w*b.z; acc[3][3] += a.w*b.w;
        }
    }
    const int nc = n0 + tn;
    if (nc >= Nn) return;
    float4 bv = make_float4(0.f, 0.f, 0.f, 0.f);
    if (bias) bv = *(const float4*)(bias + nc);
    #pragma unroll
    for (int i = 0; i < 4; ++i) {
        float4 o;
        o.x = acc[i][0] + bv.x; o.y = acc[i][1] + bv.y;
        o.z = acc[i][2] + bv.z; o.w = acc[i][3] + bv.w;
        if (RELU) { o.x=fmaxf(o.x,0.f); o.y=fmaxf(o.y,0.f); o.z=fmaxf(o.z,0.f); o.w=fmaxf(o.w,0.f); }
        *(float4*)(Y + (size_t)(m0 + tm + i) * Nn + nc) = o;
    }
}

// ---------------------------------------------------------------------------
// Batched Y[b] = (A[b] @ H[b]) * mask[b,:,None], optional ReLU.
// ---------------------------------------------------------------------------
template<int RELU>
__global__ __launch_bounds__(256) void gemm_nn_mask(const float* __restrict__ A,
    const float* __restrict__ Hm, const float* __restrict__ mask,
    float* __restrict__ Y, int M, int K, int Nn)
{
    const int b = blockIdx.z;
    A  += (size_t)b * M * K;
    Hm += (size_t)b * K * Nn;
    Y  += (size_t)b * M * Nn;
    __shared__ float As[16][68];
    __shared__ float Hs[16][68];
    const int tid = threadIdx.x;
    const int m0 = blockIdx.y << 6;
    const int n0 = blockIdx.x << 6;
    const int lr = tid >> 2;
    const int lc = (tid & 3) << 2;
    const int hr = tid >> 4;           // 0..15
    const int hc = (tid & 15) << 2;    // 0..60
    const int tm = (tid >> 4) << 2;
    const int tn = (tid & 15) << 2;

    float acc[4][4] = {{0.f,0.f,0.f,0.f},{0.f,0.f,0.f,0.f},{0.f,0.f,0.f,0.f},{0.f,0.f,0.f,0.f}};

    for (int k0 = 0; k0 < K; k0 += 16) {
        float4 av = *(const float4*)(A + (size_t)(m0 + lr) * K + k0 + lc);
        float4 hv = *(const float4*)(Hm + (size_t)(k0 + hr) * Nn + n0 + hc);
        __syncthreads();
        As[lc+0][lr]=av.x; As[lc+1][lr]=av.y; As[lc+2][lr]=av.z; As[lc+3][lr]=av.w;
        *(float4*)(&Hs[hr][hc]) = hv;
        __syncthreads();
        #pragma unroll
        for (int kk = 0; kk < 16; ++kk) {
            const float4 a = *(const float4*)(&As[kk][tm]);
            const float4 h = *(const float4*)(&Hs[kk][tn]);
            acc[0][0] += a.x*h.x; acc[0][1] += a.x*h.y; acc[0][2] += a.x*h.z; acc[0][3] += a.x*h.w;
            acc[1][0] += a.y*h.x; acc[1][1] += a.y*h.y; acc[1][2] += a.y*h.z; acc[1][3] += a.y*h.w;
            acc[2][0] += a.z*h.x; acc[2][1] += a.z*h.y; acc[2][2] += a.z*h.z; acc[2][3] += a.z*h.w;
            acc[3][0] += a.w*h.x; acc[3][1] += a.w*h.y; acc[3][2] += a.w*h.z; acc[3][3] += a.w*h.w;
        }
    }
    #pragma unroll
    for (int i = 0; i < 4; ++i) {
        const float mk = mask[b * M + m0 + tm + i];
        float4 o;
        o.x = acc[i][0]*mk; o.y = acc[i][1]*mk; o.z = acc[i][2]*mk; o.w = acc[i][3]*mk;
        if (RELU) { o.x=fmaxf(o.x,0.f); o.y=fmaxf(o.y,0.f); o.z=fmaxf(o.z,0.f); o.w=fmaxf(o.w,0.f); }
        *(float4*)(Y + (size_t)(m0 + tm + i) * Nn + n0 + tn) = o;
    }
}

// ---------------------------------------------------------------------------
__global__ __launch_bounds__(256) void attn_sisj(const float* __restrict__ h,
    const float* __restrict__ aw, const float* __restrict__ ab,
    float* __restrict__ si, float* __restrict__ sj)
{
    const int lane = threadIdx.x & 63;
    const int row  = (blockIdx.x << 2) + (threadIdx.x >> 6);
    const float4 hv = ((const float4*)(h + (size_t)row * HDIM))[lane];
    const float4 a1 = ((const float4*)aw)[lane];
    const float4 a2 = ((const float4*)(aw + HDIM))[lane];
    float s1 = hv.x*a1.x + hv.y*a1.y + hv.z*a1.z + hv.w*a1.w;
    float s2 = hv.x*a2.x + hv.y*a2.y + hv.z*a2.z + hv.w*a2.w;
    #pragma unroll
    for (int off = 32; off > 0; off >>= 1) {
        s1 += __shfl_down(s1, off);
        s2 += __shfl_down(s2, off);
    }
    if (lane == 0) { si[row] = s1 + ab[0]; sj[row] = s2; }
}

// ---------------------------------------------------------------------------
__global__ __launch_bounds__(512) void attn_score(const float* __restrict__ si,
    const float* __restrict__ sj, const float* __restrict__ adj,
    const float* __restrict__ mask, float* __restrict__ watt)
{
    const int bi = blockIdx.x;           // b*NN + i
    const int b  = bi >> 9;
    const int j  = threadIdx.x;
    const float s0 = si[bi];
    const float mi = mask[bi];
    float s = sigmoidf_(s0 + sj[(b << 9) + j]) * adj[(size_t)bi * NN + j] * mi * mask[(b << 9) + j];
    float t = s;
    #pragma unroll
    for (int off = 32; off > 0; off >>= 1) t += __shfl_down(t, off);
    __shared__ float red[8];
    const int lane = j & 63, wv = j >> 6;
    if (lane == 0) red[wv] = t;
    __syncthreads();
    if (j == 0) {
        float tot = 0.f;
        #pragma unroll
        for (int w = 0; w < 8; ++w) tot += red[w];
        red[0] = 1.0f / (tot + 1e-8f);
    }
    __syncthreads();
    watt[(size_t)bi * NN + j] = s * red[0];
}

// ---------------------------------------------------------------------------
// Pack fp32 -> f16x2 (u32). n = element pairs.
// ---------------------------------------------------------------------------
__global__ __launch_bounds__(256) void pack_f16(const float* __restrict__ src,
    unsigned int* __restrict__ dst, int n)
{
    int i = blockIdx.x * 256 + threadIdx.x;
    if (i < n) {
        float2 v = ((const float2*)src)[i];
        _Float16 a = (_Float16)v.x, b = (_Float16)v.y;
        unsigned short ua = *(unsigned short*)&a, ub = *(unsigned short*)&b;
        dst[i] = (unsigned int)ua | ((unsigned int)ub << 16);
    }
}

// ---------------------------------------------------------------------------
// Single-block-per-chain LSTM scan, f16 weights CU-resident in AGPRs.
// Grid: 16 blocks (chain = batch*2+dir), 512 threads, 2 waves/SIMD.
// History: rounds 5-7 proved the RA caps ARCH VGPRs at 128 for this kernel
// (re-streaming 768 B/thread/step from L2 = 2 us/step). Fix: give the weight
// values the AGPR register class via "a" inline-asm constraints — AGPRs share
// the unified 512-reg/wave file but are exempt from the arch-VGPR pressure
// heuristic (MFMA GEMMs keep 64-200 AGPRs resident routinely). Budget:
// 192 AGPR (weights) + ~50 VGPR (working) = 242 <= 256/wave at 2 waves/SIMD.
// The per-iteration re-pin makes the loop's weight values asm OUTPUTS, so the
// compiler cannot rematerialize the global loads inside the loop (r5/r6 bug).
// Static __shared__ (135,680 B <= gfx950's 160 KB) so the backend's occupancy
// model sees the LDS bound. Worst case +192 v_accvgpr_read/step (~0.75us/step);
// direct AGPR-src VOP3P encode would give ~0.45 us/step.
// ---------------------------------------------------------------------------
__global__ __launch_bounds__(512) __attribute__((amdgpu_waves_per_eu(2, 2)))
void lstm_scan6(
    const float* __restrict__ pre_f, const float* __restrict__ pre_b,
    const unsigned int* __restrict__ w16_f, const unsigned int* __restrict__ w16_b,
    float* __restrict__ out)
{
    __shared__ uint4v lw4[16 * 512];        // 128 KB: LDS tail of weight rows
    __shared__ float g_s[1024];             // 4 KB: gate pre-activations
    __shared__ unsigned int h2[128];        // 512 B: packed-f16 hidden state

    const int chain = blockIdx.x;
    const int batch = chain >> 1;
    const int dir   = chain & 1;
    const float* pre = dir ? pre_b : pre_f;
    const unsigned int* w = dir ? w16_b : w16_f;
    const int t0 = threadIdx.x;                    // 0..511

    const uint4v* wrA = (const uint4v*)(w + (size_t)t0 * 128);          // row t0
    const uint4v* wrB = (const uint4v*)(w + (size_t)(t0 + 512) * 128);  // row t0+512

    // LDS tail first (uint4 24..31 of each row, lane-contiguous = conflict-free)
    #pragma unroll
    for (int i = 0; i < 8; ++i) {
        lw4[i * 512 + t0]       = wrA[24 + i];
        lw4[(8 + i) * 512 + t0] = wrB[24 + i];
    }

    // Weights u32[0..95] of each row -> named values, forced into AGPR class.
#define WD(i) uint4v A##i = wrA[i]; uint4v B##i = wrB[i];
    WD(0) WD(1) WD(2) WD(3) WD(4) WD(5) WD(6) WD(7) WD(8) WD(9) WD(10) WD(11)
    WD(12) WD(13) WD(14) WD(15) WD(16) WD(17) WD(18) WD(19) WD(20) WD(21) WD(22) WD(23)
#undef WD
#define PIN_ALL \
    { \
        asm volatile("" : "+a"(A0)); asm volatile("" : "+a"(A1)); \
        asm volatile("" : "+a"(A2)); asm volatile("" : "+a"(A3)); \
        asm volatile("" : "+a"(A4)); asm volatile("" : "+a"(A5)); \
        asm volatile("" : "+a"(A6)); asm volatile("" : "+a"(A7)); \
        asm volatile("" : "+a"(A8)); asm volatile("" : "+a"(A9)); \
        asm volatile("" : "+a"(A10)); asm volatile("" : "+a"(A11)); \
        asm volatile("" : "+a"(A12)); asm volatile("" : "+a"(A13)); \
        asm volatile("" : "+a"(A14)); asm volatile("" : "+a"(A15)); \
        asm volatile("" : "+a"(A16)); asm volatile("" : "+a"(A17)); \
        asm volatile("" : "+a"(A18)); asm volatile("" : "+a"(A19)); \
        asm volatile("" : "+a"(A20)); asm volatile("" : "+a"(A21)); \
        asm volatile("" : "+a"(A22)); asm volatile("" : "+a"(A23)); \
        asm volatile("" : "+a"(B0)); asm volatile("" : "+a"(B1)); \
        asm volatile("" : "+a"(B2)); asm volatile("" : "+a"(B3)); \
        asm volatile("" : "+a"(B4)); asm volatile("" : "+a"(B5)); \
        asm volatile("" : "+a"(B6)); asm volatile("" : "+a"(B7)); \
        asm volatile("" : "+a"(B8)); asm volatile("" : "+a"(B9)); \
        asm volatile("" : "+a"(B10)); asm volatile("" : "+a"(B11)); \
        asm volatile("" : "+a"(B12)); asm volatile("" : "+a"(B13)); \
        asm volatile("" : "+a"(B14)); asm volatile("" : "+a"(B15)); \
        asm volatile("" : "+a"(B16)); asm volatile("" : "+a"(B17)); \
        asm volatile("" : "+a"(B18)); asm volatile("" : "+a"(B19)); \
        asm volatile("" : "+a"(B20)); asm volatile("" : "+a"(B21)); \
        asm volatile("" : "+a"(B22)); asm volatile("" : "+a"(B23)); \
    }
    PIN_ALL

    if (t0 < 128) h2[t0] = 0u;
    float c = 0.f;

    const int tt0 = dir ? (TT - 1) : 0;
    const long pstep = dir ? -1024 : 1024;
    const long ostep = dir ? -512 : 512;
    const float* ppA = pre + ((size_t)batch * TT + tt0) * 1024 + t0;
    const float* ppB = ppA + 512;
    float* op = out + ((size_t)batch * TT + tt0) * 512 + dir * 256 + t0;  // used by t0<256
    float pvA = *ppA; ppA += pstep;
    float pvB = *ppB; ppB += pstep;
    __syncthreads();

    for (int t = 0; t < TT; ++t) {
        PIN_ALL   // weights re-enter each iteration as AGPR-class asm outputs

        // prefetch next step's pre values early (hidden under the dots)
        float pvA_n = 0.f, pvB_n = 0.f;
        if (t + 1 < TT) { pvA_n = *ppA; pvB_n = *ppB; }
        ppA += pstep; ppB += pstep;

        float a0 = 0.f, a1 = 0.f, a2 = 0.f, a3 = 0.f;
        float b0 = 0.f, b1 = 0.f, b2 = 0.f, b3 = 0.f;
        const uint4v* h4 = (const uint4v*)h2;
#define DOT2(i) { const uint4v hv = h4[i]; \
        a0 = fdot2_(A##i.x, hv.x, a0); a1 = fdot2_(A##i.y, hv.y, a1); \
        a2 = fdot2_(A##i.z, hv.z, a2); a3 = fdot2_(A##i.w, hv.w, a3); \
        b0 = fdot2_(B##i.x, hv.x, b0); b1 = fdot2_(B##i.y, hv.y, b1); \
        b2 = fdot2_(B##i.z, hv.z, b2); b3 = fdot2_(B##i.w, hv.w, b3); }
        DOT2(0) DOT2(1) DOT2(2) DOT2(3) DOT2(4) DOT2(5) DOT2(6) DOT2(7)
        DOT2(8) DOT2(9) DOT2(10) DOT2(11) DOT2(12) DOT2(13) DOT2(14) DOT2(15)
        DOT2(16) DOT2(17) DOT2(18) DOT2(19) DOT2(20) DOT2(21) DOT2(22) DOT2(23)
#undef DOT2
        #pragma unroll
        for (int i = 0; i < 8; ++i) {
            const uint4v wa = lw4[i * 512 + t0];
            const uint4v wb = lw4[(8 + i) * 512 + t0];
            const uint4v hv = h4[24 + i];
            a0 = fdot2_(wa.x, hv.x, a0); a1 = fdot2_(wa.y, hv.y, a1);
            a2 = fdot2_(wa.z, hv.z, a2); a3 = fdot2_(wa.w, hv.w, a3);
            b0 = fdot2_(wb.x, hv.x, b0); b1 = fdot2_(wb.y, hv.y, b1);
            b2 = fdot2_(wb.z, hv.z, b2); b3 = fdot2_(wb.w, hv.w, b3);
        }
        g_s[t0]       = (a0 + a1) + (a2 + a3) + pvA;
        g_s[512 + t0] = (b0 + b1) + (b2 + b3) + pvB;
        __syncthreads();
        if (t0 < 256) {
            const float ig = sigmoidf_(g_s[t0]);
            const float fg = sigmoidf_(g_s[256 + t0]);
            const float gg = tanhf_(g_s[512 + t0]);
            const float og = sigmoidf_(g_s[768 + t0]);
            c = fg * c + ig * gg;
            const float h = og * tanhf_(c);
            *op = h;
            op += ostep;
            _Float16 hh = (_Float16)h;
            ((unsigned short*)h2)[t0] = *(unsigned short*)&hh;
        }
        pvA = pvA_n; pvB = pvB_n;
        __syncthreads();
    }
#undef PIN_ALL
}

// ---------------------------------------------------------------------------

extern "C" void kernel_launch(void* const* d_in, const int* in_sizes, int n_in,
                              void* d_out, int out_size, void* d_ws, size_t ws_size,
                              hipStream_t stream)
{
    const float* nf   = (const float*)d_in[0];
    const float* adj  = (const float*)d_in[1];
    const float* mask = (const float*)d_in[2];
    const float* g_w[3]  = {(const float*)d_in[4],  (const float*)d_in[8],  (const float*)d_in[12]};
    const float* g_b[3]  = {(const float*)d_in[5],  (const float*)d_in[9],  (const float*)d_in[13]};
    const float* g_aw[3] = {(const float*)d_in[6],  (const float*)d_in[10], (const float*)d_in[14]};
    const float* g_ab[3] = {(const float*)d_in[7],  (const float*)d_in[11], (const float*)d_in[15]};
    const float* wih0f = (const float*)d_in[16]; const float* whh0f = (const float*)d_in[17]; const float* b0f = (const float*)d_in[18];
    const float* wih0b = (const float*)d_in[19]; const float* whh0b = (const float*)d_in[20]; const float* b0b = (const float*)d_in[21];
    const float* wih1f = (const float*)d_in[22]; const float* whh1f = (const float*)d_in[23]; const float* b1f = (const float*)d_in[24];
    const float* wih1b = (const float*)d_in[25]; const float* whh1b = (const float*)d_in[26]; const float* b1b = (const float*)d_in[27];

    float* ws = (float*)d_ws;
    // Workspace layout (floats); total ~15.7M floats = ~63 MB
    float* bufA = ws;                       // (4096,256)  GNN h projection / head tmp
    float* bufB = bufA + 1048576;           // (4096,256)  GNN layer output; later f16 weights
    float* bufC = bufB + 1048576;           // (4096,256)  GNN3 output (kept for nd head)
    float* si   = bufC + 1048576;           // (4096)
    float* sj   = si + 4096;                // (4096)
    float* out0 = sj + 4096;                // (4096,512) LSTM layer0 output
    float* out1 = out0 + 2097152;           // (4096,512) LSTM layer1 output
    float* P0   = out1 + 2097152;           // (4096,1024) pre-activations fwd
    float* P1   = P0 + 4194304;             // (4096,1024) pre-activations bwd
    float* watt = P0;                       // alias: attention weights (GNN phase only)
    // packed f16 whh weights, aliased onto bufB (dead after GNN3):
    unsigned int* w16_0f = (unsigned int*)bufB;
    unsigned int* w16_0b = w16_0f + 131072;
    unsigned int* w16_1f = w16_0b + 131072;
    unsigned int* w16_1b = w16_1f + 131072;

    const int MR = BB * NN;                 // 4096 rows
    dim3 blk(256);

    // ---------------- GNN x3 ----------------
    auto run_gnn = [&](const float* xin, int Kin, int li, float* ob, bool relu) {
        gemm_nt<0><<<dim3(HDIM / 64, MR / 64), blk, 0, stream>>>(xin, g_w[li], g_b[li], bufA, MR, Kin, HDIM);
        attn_sisj<<<dim3(MR / 4), blk, 0, stream>>>(bufA, g_aw[li], g_ab[li], si, sj);
        attn_score<<<dim3(MR), dim3(512), 0, stream>>>(si, sj, adj, mask, watt);
        if (relu)
            gemm_nn_mask<1><<<dim3(HDIM / 64, NN / 64, BB), blk, 0, stream>>>(watt, bufA, mask, ob, NN, NN, HDIM);
        else
            gemm_nn_mask<0><<<dim3(HDIM / 64, NN / 64, BB), blk, 0, stream>>>(watt, bufA, mask, ob, NN, NN, HDIM);
    };
    run_gnn(nf,   NDIM, 0, bufB, true);
    run_gnn(bufB, HDIM, 1, bufB, true);
    run_gnn(bufB, HDIM, 2, bufC, false);

    // ---------------- pack whh weights to f16 (bufB now dead) ----------------
    pack_f16<<<dim3(512), blk, 0, stream>>>(whh0f, w16_0f, 131072);
    pack_f16<<<dim3(512), blk, 0, stream>>>(whh0b, w16_0b, 131072);
    pack_f16<<<dim3(512), blk, 0, stream>>>(whh1f, w16_1f, 131072);
    pack_f16<<<dim3(512), blk, 0, stream>>>(whh1b, w16_1b, 131072);

    // ---------------- LSTM layer 0 ----------------
    gemm_nt<0><<<dim3(16, MR / 64), blk, 0, stream>>>(bufC, wih0f, b0f, P0, MR, HDIM, 1024);
    gemm_nt<0><<<dim3(16, MR / 64), blk, 0, stream>>>(bufC, wih0b, b0b, P1, MR, HDIM, 1024);
    lstm_scan6<<<dim3(16), dim3(512), 0, stream>>>(P0, P1, w16_0f, w16_0b, out0);

    // ---------------- LSTM layer 1 ----------------
    gemm_nt<0><<<dim3(16, MR / 64), blk, 0, stream>>>(out0, wih1f, b1f, P0, MR, 512, 1024);
    gemm_nt<0><<<dim3(16, MR / 64), blk, 0, stream>>>(out0, wih1b, b1b, P1, MR, 512, 1024);
    lstm_scan6<<<dim3(16), dim3(512), 0, stream>>>(P0, P1, w16_1f, w16_1b, out1);

    // ---------------- Heads ----------------
    float* out = (float*)d_out;
    // op: (B,N,64) at offset 0
    gemm_nt<1><<<dim3(4, MR / 64), blk, 0, stream>>>(out1, (const float*)d_in[28], (const float*)d_in[29], bufA, MR, 512, 256);
    gemm_nt<0><<<dim3(1, MR / 64), blk, 0, stream>>>(bufA, (const float*)d_in[30], (const float*)d_in[31], out, MR, 256, 64);
    // pp: (B,N,16) at offset 262144
    gemm_nt<1><<<dim3(4, MR / 64), blk, 0, stream>>>(out1, (const float*)d_in[32], (const float*)d_in[33], bufA, MR, 512, 256);
    gemm_nt<0><<<dim3(1, MR / 64), blk, 0, stream>>>(bufA, (const float*)d_in[34], (const float*)d_in[35], out + 262144, MR, 256, 16);
    // sk: (B,N,128) at offset 327680
    gemm_nt<1><<<dim3(4, MR / 64), blk, 0, stream>>>(out1, (const float*)d_in[36], (const float*)d_in[37], bufA, MR, 512, 256);
    gemm_nt<0><<<dim3(2, MR / 64), blk, 0, stream>>>(bufA, (const float*)d_in[38], (const float*)d_in[39], out + 327680, MR, 256, 128);
    // nd: (B,N,128) at offset 851968 (input = GNN3 output)
    gemm_nt<1><<<dim3(4, MR / 64), blk, 0, stream>>>(bufC, (const float*)d_in[40], (const float*)d_in[41], bufA, MR, 256, 256);
    gemm_nt<0><<<dim3(2, MR / 64), blk, 0, stream>>>(bufA, (const float*)d_in[42], (const float*)d_in[43], out + 851968, MR, 256, 128);
}

// Round 9
// 2543.166 us; speedup vs baseline: 2.9457x; 2.9457x over previous
//
#include <hip/hip_runtime.h>

// Problem constants (DeepCAD_1958505087412)
#define BB   8
#define NN   512      // nodes == timesteps
#define NDIM 128
#define HDIM 256      // GNN out dim == LSTM hidden
#define TT   512

__device__ __forceinline__ float sigmoidf_(float x) { return 1.0f / (1.0f + __expf(-x)); }
__device__ __forceinline__ float tanhf_(float x) { float e = __expf(2.0f * x); return 1.0f - 2.0f / (e + 1.0f); }

typedef _Float16 half2v __attribute__((ext_vector_type(2)));
typedef unsigned int uint4v __attribute__((ext_vector_type(4)));
__device__ __forceinline__ float fdot2_(unsigned int w, unsigned int h, float acc) {
    return __builtin_amdgcn_fdot2(__builtin_bit_cast(half2v, w),
                                  __builtin_bit_cast(half2v, h), acc, false);
}

// ---------------------------------------------------------------------------
// Y = X @ W^T + bias (optional ReLU). X:(M,K) W:(Nn,K) Y:(M,Nn) row-major.
// ---------------------------------------------------------------------------
template<int RELU>
__global__ __launch_bounds__(256) void gemm_nt(const float* __restrict__ X,
    const float* __restrict__ W, const float* __restrict__ bias,
    float* __restrict__ Y, int M, int K, int Nn)
{
    __shared__ float Xs[16][68];
    __shared__ float Ws[16][68];
    const int tid = threadIdx.x;
    const int m0 = blockIdx.y << 6;
    const int n0 = blockIdx.x << 6;
    const int lr = tid >> 2;           // 0..63
    const int lc = (tid & 3) << 2;     // 0,4,8,12
    const int tm = (tid >> 4) << 2;    // 0..60
    const int tn = (tid & 15) << 2;    // 0..60

    float acc[4][4] = {{0.f,0.f,0.f,0.f},{0.f,0.f,0.f,0.f},{0.f,0.f,0.f,0.f},{0.f,0.f,0.f,0.f}};

    const float* Xp = X + (size_t)(m0 + lr) * K + lc;
    const bool wok = (n0 + lr) < Nn;
    const float* Wp = wok ? (W + (size_t)(n0 + lr) * K + lc) : W;

    for (int k0 = 0; k0 < K; k0 += 16) {
        float4 xv = *(const float4*)(Xp + k0);
        float4 wv = *(const float4*)(Wp + k0);
        if (!wok) wv = make_float4(0.f, 0.f, 0.f, 0.f);
        __syncthreads();
        Xs[lc+0][lr]=xv.x; Xs[lc+1][lr]=xv.y; Xs[lc+2][lr]=xv.z; Xs[lc+3][lr]=xv.w;
        Ws[lc+0][lr]=wv.x; Ws[lc+1][lr]=wv.y; Ws[lc+2][lr]=wv.z; Ws[lc+3][lr]=wv.w;
        __syncthreads();
        #pragma unroll
        for (int kk = 0; kk < 16; ++kk) {
            const float4 a = *(const float4*)(&Xs[kk][tm]);
            const float4 b = *(const float4*)(&Ws[kk][tn]);
            acc[0][0] += a.x*b.x; acc[0][1] += a.x*b.y; acc[0][2] += a.x*b.z; acc[0][3] += a.x*b.w;
            acc[1][0] += a.y*b.x; acc[1][1] += a.y*b.y; acc[1][2] += a.y*b.z; acc[1][3] += a.y*b.w;
            acc[2][0] += a.z*b.x; acc[2][1] += a.z*b.y; acc[2][2] += a.z*b.z; acc[2][3] += a.z*b.w;
            acc[3][0] += a.w*b.x; acc[3][1] += a.w*b.y; acc[3][2] += a.w*b.z; acc[3][3] += a.w*b.w;
        }
    }
    const int nc = n0 + tn;
    if (nc >= Nn) return;
    float4 bv = make_float4(0.f, 0.f, 0.f, 0.f);
    if (bias) bv = *(const float4*)(bias + nc);
    #pragma unroll
    for (int i = 0; i < 4; ++i) {
        float4 o;
        o.x = acc[i][0] + bv.x; o.y = acc[i][1] + bv.y;
        o.z = acc[i][2] + bv.z; o.w = acc[i][3] + bv.w;
        if (RELU) { o.x=fmaxf(o.x,0.f); o.y=fmaxf(o.y,0.f); o.z=fmaxf(o.z,0.f); o.w=fmaxf(o.w,0.f); }
        *(float4*)(Y + (size_t)(m0 + tm + i) * Nn + nc) = o;
    }
}

// ---------------------------------------------------------------------------
// Batched Y[b] = (A[b] @ H[b]) * mask[b,:,None], optional ReLU.
// ---------------------------------------------------------------------------
template<int RELU>
__global__ __launch_bounds__(256) void gemm_nn_mask(const float* __restrict__ A,
    const float* __restrict__ Hm, const float* __restrict__ mask,
    float* __restrict__ Y, int M, int K, int Nn)
{
    const int b = blockIdx.z;
    A  += (size_t)b * M * K;
    Hm += (size_t)b * K * Nn;
    Y  += (size_t)b * M * Nn;
    __shared__ float As[16][68];
    __shared__ float Hs[16][68];
    const int tid = threadIdx.x;
    const int m0 = blockIdx.y << 6;
    const int n0 = blockIdx.x << 6;
    const int lr = tid >> 2;
    const int lc = (tid & 3) << 2;
    const int hr = tid >> 4;           // 0..15
    const int hc = (tid & 15) << 2;    // 0..60
    const int tm = (tid >> 4) << 2;
    const int tn = (tid & 15) << 2;

    float acc[4][4] = {{0.f,0.f,0.f,0.f},{0.f,0.f,0.f,0.f},{0.f,0.f,0.f,0.f},{0.f,0.f,0.f,0.f}};

    for (int k0 = 0; k0 < K; k0 += 16) {
        float4 av = *(const float4*)(A + (size_t)(m0 + lr) * K + k0 + lc);
        float4 hv = *(const float4*)(Hm + (size_t)(k0 + hr) * Nn + n0 + hc);
        __syncthreads();
        As[lc+0][lr]=av.x; As[lc+1][lr]=av.y; As[lc+2][lr]=av.z; As[lc+3][lr]=av.w;
        *(float4*)(&Hs[hr][hc]) = hv;
        __syncthreads();
        #pragma unroll
        for (int kk = 0; kk < 16; ++kk) {
            const float4 a = *(const float4*)(&As[kk][tm]);
            const float4 h = *(const float4*)(&Hs[kk][tn]);
            acc[0][0] += a.x*h.x; acc[0][1] += a.x*h.y; acc[0][2] += a.x*h.z; acc[0][3] += a.x*h.w;
            acc[1][0] += a.y*h.x; acc[1][1] += a.y*h.y; acc[1][2] += a.y*h.z; acc[1][3] += a.y*h.w;
            acc[2][0] += a.z*h.x; acc[2][1] += a.z*h.y; acc[2][2] += a.z*h.z; acc[2][3] += a.z*h.w;
            acc[3][0] += a.w*h.x; acc[3][1] += a.w*h.y; acc[3][2] += a.w*h.z; acc[3][3] += a.w*h.w;
        }
    }
    #pragma unroll
    for (int i = 0; i < 4; ++i) {
        const float mk = mask[b * M + m0 + tm + i];
        float4 o;
        o.x = acc[i][0]*mk; o.y = acc[i][1]*mk; o.z = acc[i][2]*mk; o.w = acc[i][3]*mk;
        if (RELU) { o.x=fmaxf(o.x,0.f); o.y=fmaxf(o.y,0.f); o.z=fmaxf(o.z,0.f); o.w=fmaxf(o.w,0.f); }
        *(float4*)(Y + (size_t)(m0 + tm + i) * Nn + n0 + tn) = o;
    }
}

// ---------------------------------------------------------------------------
__global__ __launch_bounds__(256) void attn_sisj(const float* __restrict__ h,
    const float* __restrict__ aw, const float* __restrict__ ab,
    float* __restrict__ si, float* __restrict__ sj)
{
    const int lane = threadIdx.x & 63;
    const int row  = (blockIdx.x << 2) + (threadIdx.x >> 6);
    const float4 hv = ((const float4*)(h + (size_t)row * HDIM))[lane];
    const float4 a1 = ((const float4*)aw)[lane];
    const float4 a2 = ((const float4*)(aw + HDIM))[lane];
    float s1 = hv.x*a1.x + hv.y*a1.y + hv.z*a1.z + hv.w*a1.w;
    float s2 = hv.x*a2.x + hv.y*a2.y + hv.z*a2.z + hv.w*a2.w;
    #pragma unroll
    for (int off = 32; off > 0; off >>= 1) {
        s1 += __shfl_down(s1, off);
        s2 += __shfl_down(s2, off);
    }
    if (lane == 0) { si[row] = s1 + ab[0]; sj[row] = s2; }
}

// ---------------------------------------------------------------------------
__global__ __launch_bounds__(512) void attn_score(const float* __restrict__ si,
    const float* __restrict__ sj, const float* __restrict__ adj,
    const float* __restrict__ mask, float* __restrict__ watt)
{
    const int bi = blockIdx.x;           // b*NN + i
    const int b  = bi >> 9;
    const int j  = threadIdx.x;
    const float s0 = si[bi];
    const float mi = mask[bi];
    float s = sigmoidf_(s0 + sj[(b << 9) + j]) * adj[(size_t)bi * NN + j] * mi * mask[(b << 9) + j];
    float t = s;
    #pragma unroll
    for (int off = 32; off > 0; off >>= 1) t += __shfl_down(t, off);
    __shared__ float red[8];
    const int lane = j & 63, wv = j >> 6;
    if (lane == 0) red[wv] = t;
    __syncthreads();
    if (j == 0) {
        float tot = 0.f;
        #pragma unroll
        for (int w = 0; w < 8; ++w) tot += red[w];
        red[0] = 1.0f / (tot + 1e-8f);
    }
    __syncthreads();
    watt[(size_t)bi * NN + j] = s * red[0];
}

// ---------------------------------------------------------------------------
// Pack fp32 -> f16x2 (u32). n = element pairs.
// ---------------------------------------------------------------------------
__global__ __launch_bounds__(256) void pack_f16(const float* __restrict__ src,
    unsigned int* __restrict__ dst, int n)
{
    int i = blockIdx.x * 256 + threadIdx.x;
    if (i < n) {
        float2 v = ((const float2*)src)[i];
        _Float16 a = (_Float16)v.x, b = (_Float16)v.y;
        unsigned short ua = *(unsigned short*)&a, ub = *(unsigned short*)&b;
        dst[i] = (unsigned int)ua | ((unsigned int)ub << 16);
    }
}

// ---------------------------------------------------------------------------
// Single-block-per-chain LSTM scan, f16 weights CU-resident — 1024-thread cut.
// Residency history: r5 (this geometry, no pins) -> loads remat'd into loop;
// r6/r7 (512 thr, 192 dwords/thread pinned) -> demand 224 > the 128-reg budget
// the RA grants -> spills; r8 ("a" class) -> accvgpr copy storm. This round:
// 1024 threads => only 96 weight-dwords/thread, so demand (96 + ~25 working)
// FITS the NATURAL 128-VGPR budget at the LDS-forced occupancy (static 133 KB
// LDS -> 1 block/CU = 16 waves = 4 waves/SIMD). "+v" pins re-applied per
// iteration stop rematerialization (r5's bug); no exotic budget request.
// Thread t owns gate row t: u32[0..23] in named pinned regs, u32[24..31] in
// LDS (lane-contiguous ds_read_b128, conflict-free). h packed f16 in LDS
// (broadcast). 128 v_dot2_f32_f16/thread/step.
// ---------------------------------------------------------------------------
__global__ __launch_bounds__(1024) __attribute__((amdgpu_waves_per_eu(4, 4)))
void lstm_scan7(
    const float* __restrict__ pre_f, const float* __restrict__ pre_b,
    const unsigned int* __restrict__ w16_f, const unsigned int* __restrict__ w16_b,
    float* __restrict__ out)
{
    __shared__ uint4v lw4[8 * 1024];        // 128 KB: LDS tail of weight rows
    __shared__ float g_s[1024];             // 4 KB: gate pre-activations
    __shared__ unsigned int h2[128];        // 512 B: packed-f16 hidden state

    const int chain = blockIdx.x;
    const int batch = chain >> 1;
    const int dir   = chain & 1;
    const float* pre = dir ? pre_b : pre_f;
    const unsigned int* w = dir ? w16_b : w16_f;
    const int t0 = threadIdx.x;                    // gate row 0..1023

    const uint4v* wr = (const uint4v*)(w + (size_t)t0 * 128);

    // LDS tail (uint4 24..31 of each row, lane-contiguous = conflict-free)
    #pragma unroll
    for (int i = 0; i < 8; ++i) lw4[i * 1024 + t0] = wr[24 + i];

    // u32[0..95] -> 24 named uint4 registers
#define WD(i) uint4v W##i = wr[i];
    WD(0) WD(1) WD(2) WD(3) WD(4) WD(5) WD(6) WD(7) WD(8) WD(9) WD(10) WD(11)
    WD(12) WD(13) WD(14) WD(15) WD(16) WD(17) WD(18) WD(19) WD(20) WD(21) WD(22) WD(23)
#undef WD
#define PIN_ALL \
    { \
        asm volatile("" : "+v"(W0)); asm volatile("" : "+v"(W1)); \
        asm volatile("" : "+v"(W2)); asm volatile("" : "+v"(W3)); \
        asm volatile("" : "+v"(W4)); asm volatile("" : "+v"(W5)); \
        asm volatile("" : "+v"(W6)); asm volatile("" : "+v"(W7)); \
        asm volatile("" : "+v"(W8)); asm volatile("" : "+v"(W9)); \
        asm volatile("" : "+v"(W10)); asm volatile("" : "+v"(W11)); \
        asm volatile("" : "+v"(W12)); asm volatile("" : "+v"(W13)); \
        asm volatile("" : "+v"(W14)); asm volatile("" : "+v"(W15)); \
        asm volatile("" : "+v"(W16)); asm volatile("" : "+v"(W17)); \
        asm volatile("" : "+v"(W18)); asm volatile("" : "+v"(W19)); \
        asm volatile("" : "+v"(W20)); asm volatile("" : "+v"(W21)); \
        asm volatile("" : "+v"(W22)); asm volatile("" : "+v"(W23)); \
    }
    PIN_ALL

    if (t0 < 128) h2[t0] = 0u;
    float c = 0.f;

    const int tt0 = dir ? (TT - 1) : 0;
    const long pstep = dir ? -1024 : 1024;
    const long ostep = dir ? -512 : 512;
    const float* pp = pre + ((size_t)batch * TT + tt0) * 1024 + t0;
    float* op = out + ((size_t)batch * TT + tt0) * 512 + dir * 256 + t0;  // used by t0<256
    float pv = *pp; pp += pstep;
    __syncthreads();

    for (int t = 0; t < TT; ++t) {
        PIN_ALL   // weight values re-enter each iteration as asm outputs: no remat

        // prefetch next step's pre value (hidden under the dots)
        float pv_n = 0.f;
        if (t + 1 < TT) pv_n = *pp;
        pp += pstep;

        float a0 = 0.f, a1 = 0.f, a2 = 0.f, a3 = 0.f;
        const uint4v* h4 = (const uint4v*)h2;
#define DOT(i) { const uint4v hv = h4[i]; \
        a0 = fdot2_(W##i.x, hv.x, a0); a1 = fdot2_(W##i.y, hv.y, a1); \
        a2 = fdot2_(W##i.z, hv.z, a2); a3 = fdot2_(W##i.w, hv.w, a3); }
        DOT(0) DOT(1) DOT(2) DOT(3) DOT(4) DOT(5) DOT(6) DOT(7)
        DOT(8) DOT(9) DOT(10) DOT(11) DOT(12) DOT(13) DOT(14) DOT(15)
        DOT(16) DOT(17) DOT(18) DOT(19) DOT(20) DOT(21) DOT(22) DOT(23)
#undef DOT
        #pragma unroll
        for (int i = 0; i < 8; ++i) {
            const uint4v wv = lw4[i * 1024 + t0];
            const uint4v hv = h4[24 + i];
            a0 = fdot2_(wv.x, hv.x, a0); a1 = fdot2_(wv.y, hv.y, a1);
            a2 = fdot2_(wv.z, hv.z, a2); a3 = fdot2_(wv.w, hv.w, a3);
        }
        g_s[t0] = (a0 + a1) + (a2 + a3) + pv;
        __syncthreads();
        if (t0 < 256) {
            const float ig = sigmoidf_(g_s[t0]);
            const float fg = sigmoidf_(g_s[256 + t0]);
            const float gg = tanhf_(g_s[512 + t0]);
            const float og = sigmoidf_(g_s[768 + t0]);
            c = fg * c + ig * gg;
            const float h = og * tanhf_(c);
            *op = h;
            op += ostep;
            _Float16 hh = (_Float16)h;
            ((unsigned short*)h2)[t0] = *(unsigned short*)&hh;
        }
        pv = pv_n;
        __syncthreads();
    }
#undef PIN_ALL
}

// ---------------------------------------------------------------------------

extern "C" void kernel_launch(void* const* d_in, const int* in_sizes, int n_in,
                              void* d_out, int out_size, void* d_ws, size_t ws_size,
                              hipStream_t stream)
{
    const float* nf   = (const float*)d_in[0];
    const float* adj  = (const float*)d_in[1];
    const float* mask = (const float*)d_in[2];
    const float* g_w[3]  = {(const float*)d_in[4],  (const float*)d_in[8],  (const float*)d_in[12]};
    const float* g_b[3]  = {(const float*)d_in[5],  (const float*)d_in[9],  (const float*)d_in[13]};
    const float* g_aw[3] = {(const float*)d_in[6],  (const float*)d_in[10], (const float*)d_in[14]};
    const float* g_ab[3] = {(const float*)d_in[7],  (const float*)d_in[11], (const float*)d_in[15]};
    const float* wih0f = (const float*)d_in[16]; const float* whh0f = (const float*)d_in[17]; const float* b0f = (const float*)d_in[18];
    const float* wih0b = (const float*)d_in[19]; const float* whh0b = (const float*)d_in[20]; const float* b0b = (const float*)d_in[21];
    const float* wih1f = (const float*)d_in[22]; const float* whh1f = (const float*)d_in[23]; const float* b1f = (const float*)d_in[24];
    const float* wih1b = (const float*)d_in[25]; const float* whh1b = (const float*)d_in[26]; const float* b1b = (const float*)d_in[27];

    float* ws = (float*)d_ws;
    // Workspace layout (floats); total ~15.7M floats = ~63 MB
    float* bufA = ws;                       // (4096,256)  GNN h projection / head tmp
    float* bufB = bufA + 1048576;           // (4096,256)  GNN layer output; later f16 weights
    float* bufC = bufB + 1048576;           // (4096,256)  GNN3 output (kept for nd head)
    float* si   = bufC + 1048576;           // (4096)
    float* sj   = si + 4096;                // (4096)
    float* out0 = sj + 4096;                // (4096,512) LSTM layer0 output
    float* out1 = out0 + 2097152;           // (4096,512) LSTM layer1 output
    float* P0   = out1 + 2097152;           // (4096,1024) pre-activations fwd
    float* P1   = P0 + 4194304;             // (4096,1024) pre-activations bwd
    float* watt = P0;                       // alias: attention weights (GNN phase only)
    // packed f16 whh weights, aliased onto bufB (dead after GNN3):
    unsigned int* w16_0f = (unsigned int*)bufB;
    unsigned int* w16_0b = w16_0f + 131072;
    unsigned int* w16_1f = w16_0b + 131072;
    unsigned int* w16_1b = w16_1f + 131072;

    const int MR = BB * NN;                 // 4096 rows
    dim3 blk(256);

    // ---------------- GNN x3 ----------------
    auto run_gnn = [&](const float* xin, int Kin, int li, float* ob, bool relu) {
        gemm_nt<0><<<dim3(HDIM / 64, MR / 64), blk, 0, stream>>>(xin, g_w[li], g_b[li], bufA, MR, Kin, HDIM);
        attn_sisj<<<dim3(MR / 4), blk, 0, stream>>>(bufA, g_aw[li], g_ab[li], si, sj);
        attn_score<<<dim3(MR), dim3(512), 0, stream>>>(si, sj, adj, mask, watt);
        if (relu)
            gemm_nn_mask<1><<<dim3(HDIM / 64, NN / 64, BB), blk, 0, stream>>>(watt, bufA, mask, ob, NN, NN, HDIM);
        else
            gemm_nn_mask<0><<<dim3(HDIM / 64, NN / 64, BB), blk, 0, stream>>>(watt, bufA, mask, ob, NN, NN, HDIM);
    };
    run_gnn(nf,   NDIM, 0, bufB, true);
    run_gnn(bufB, HDIM, 1, bufB, true);
    run_gnn(bufB, HDIM, 2, bufC, false);

    // ---------------- pack whh weights to f16 (bufB now dead) ----------------
    pack_f16<<<dim3(512), blk, 0, stream>>>(whh0f, w16_0f, 131072);
    pack_f16<<<dim3(512), blk, 0, stream>>>(whh0b, w16_0b, 131072);
    pack_f16<<<dim3(512), blk, 0, stream>>>(whh1f, w16_1f, 131072);
    pack_f16<<<dim3(512), blk, 0, stream>>>(whh1b, w16_1b, 131072);

    // ---------------- LSTM layer 0 ----------------
    gemm_nt<0><<<dim3(16, MR / 64), blk, 0, stream>>>(bufC, wih0f, b0f, P0, MR, HDIM, 1024);
    gemm_nt<0><<<dim3(16, MR / 64), blk, 0, stream>>>(bufC, wih0b, b0b, P1, MR, HDIM, 1024);
    lstm_scan7<<<dim3(16), dim3(1024), 0, stream>>>(P0, P1, w16_0f, w16_0b, out0);

    // ---------------- LSTM layer 1 ----------------
    gemm_nt<0><<<dim3(16, MR / 64), blk, 0, stream>>>(out0, wih1f, b1f, P0, MR, 512, 1024);
    gemm_nt<0><<<dim3(16, MR / 64), blk, 0, stream>>>(out0, wih1b, b1b, P1, MR, 512, 1024);
    lstm_scan7<<<dim3(16), dim3(1024), 0, stream>>>(P0, P1, w16_1f, w16_1b, out1);

    // ---------------- Heads ----------------
    float* out = (float*)d_out;
    // op: (B,N,64) at offset 0
    gemm_nt<1><<<dim3(4, MR / 64), blk, 0, stream>>>(out1, (const float*)d_in[28], (const float*)d_in[29], bufA, MR, 512, 256);
    gemm_nt<0><<<dim3(1, MR / 64), blk, 0, stream>>>(bufA, (const float*)d_in[30], (const float*)d_in[31], out, MR, 256, 64);
    // pp: (B,N,16) at offset 262144
    gemm_nt<1><<<dim3(4, MR / 64), blk, 0, stream>>>(out1, (const float*)d_in[32], (const float*)d_in[33], bufA, MR, 512, 256);
    gemm_nt<0><<<dim3(1, MR / 64), blk, 0, stream>>>(bufA, (const float*)d_in[34], (const float*)d_in[35], out + 262144, MR, 256, 16);
    // sk: (B,N,128) at offset 327680
    gemm_nt<1><<<dim3(4, MR / 64), blk, 0, stream>>>(out1, (const float*)d_in[36], (const float*)d_in[37], bufA, MR, 512, 256);
    gemm_nt<0><<<dim3(2, MR / 64), blk, 0, stream>>>(bufA, (const float*)d_in[38], (const float*)d_in[39], out + 327680, MR, 256, 128);
    // nd: (B,N,128) at offset 851968 (input = GNN3 output)
    gemm_nt<1><<<dim3(4, MR / 64), blk, 0, stream>>>(bufC, (const float*)d_in[40], (const float*)d_in[41], bufA, MR, 256, 256);
    gemm_nt<0><<<dim3(2, MR / 64), blk, 0, stream>>>(bufA, (const float*)d_in[42], (const float*)d_in[43], out + 851968, MR, 256, 128);
}

// Round 11
// 2365.384 us; speedup vs baseline: 3.1671x; 1.0752x over previous
//
#include <hip/hip_runtime.h>

// Problem constants (DeepCAD_1958505087412)
#define BB   8
#define NN   512      // nodes == timesteps
#define NDIM 128
#define HDIM 256      // GNN out dim == LSTM hidden
#define TT   512

__device__ __forceinline__ float sigmoidf_(float x) { return 1.0f / (1.0f + __expf(-x)); }
__device__ __forceinline__ float tanhf_(float x) { float e = __expf(2.0f * x); return 1.0f - 2.0f / (e + 1.0f); }

typedef _Float16 half2v __attribute__((ext_vector_type(2)));
typedef unsigned int uint4v __attribute__((ext_vector_type(4)));
typedef short bf16x8 __attribute__((ext_vector_type(8)));
typedef float f32x4 __attribute__((ext_vector_type(4)));
__device__ __forceinline__ float fdot2_(unsigned int w, unsigned int h, float acc) {
    return __builtin_amdgcn_fdot2(__builtin_bit_cast(half2v, w),
                                  __builtin_bit_cast(half2v, h), acc, false);
}
__device__ __forceinline__ unsigned short f2bf_(float x) {
    unsigned int u = __builtin_bit_cast(unsigned int, x);
    return (unsigned short)((u + 0x7FFFu + ((u >> 16) & 1u)) >> 16);   // RNE
}

// ---------------------------------------------------------------------------
// fp32 Y = X @ W^T + bias (optional ReLU) — kept for small head layer-2 GEMMs.
// ---------------------------------------------------------------------------
template<int RELU>
__global__ __launch_bounds__(256) void gemm_nt(const float* __restrict__ X,
    const float* __restrict__ W, const float* __restrict__ bias,
    float* __restrict__ Y, int M, int K, int Nn)
{
    __shared__ float Xs[16][68];
    __shared__ float Ws[16][68];
    const int tid = threadIdx.x;
    const int m0 = blockIdx.y << 6;
    const int n0 = blockIdx.x << 6;
    const int lr = tid >> 2;
    const int lc = (tid & 3) << 2;
    const int tm = (tid >> 4) << 2;
    const int tn = (tid & 15) << 2;

    float acc[4][4] = {{0.f,0.f,0.f,0.f},{0.f,0.f,0.f,0.f},{0.f,0.f,0.f,0.f},{0.f,0.f,0.f,0.f}};

    const float* Xp = X + (size_t)(m0 + lr) * K + lc;
    const bool wok = (n0 + lr) < Nn;
    const float* Wp = wok ? (W + (size_t)(n0 + lr) * K + lc) : W;

    for (int k0 = 0; k0 < K; k0 += 16) {
        float4 xv = *(const float4*)(Xp + k0);
        float4 wv = *(const float4*)(Wp + k0);
        if (!wok) wv = make_float4(0.f, 0.f, 0.f, 0.f);
        __syncthreads();
        Xs[lc+0][lr]=xv.x; Xs[lc+1][lr]=xv.y; Xs[lc+2][lr]=xv.z; Xs[lc+3][lr]=xv.w;
        Ws[lc+0][lr]=wv.x; Ws[lc+1][lr]=wv.y; Ws[lc+2][lr]=wv.z; Ws[lc+3][lr]=wv.w;
        __syncthreads();
        #pragma unroll
        for (int kk = 0; kk < 16; ++kk) {
            const float4 a = *(const float4*)(&Xs[kk][tm]);
            const float4 b = *(const float4*)(&Ws[kk][tn]);
            acc[0][0] += a.x*b.x; acc[0][1] += a.x*b.y; acc[0][2] += a.x*b.z; acc[0][3] += a.x*b.w;
            acc[1][0] += a.y*b.x; acc[1][1] += a.y*b.y; acc[1][2] += a.y*b.z; acc[1][3] += a.y*b.w;
            acc[2][0] += a.z*b.x; acc[2][1] += a.z*b.y; acc[2][2] += a.z*b.z; acc[2][3] += a.z*b.w;
            acc[3][0] += a.w*b.x; acc[3][1] += a.w*b.y; acc[3][2] += a.w*b.z; acc[3][3] += a.w*b.w;
        }
    }
    const int nc = n0 + tn;
    if (nc >= Nn) return;
    float4 bv = make_float4(0.f, 0.f, 0.f, 0.f);
    if (bias) bv = *(const float4*)(bias + nc);
    #pragma unroll
    for (int i = 0; i < 4; ++i) {
        float4 o;
        o.x = acc[i][0] + bv.x; o.y = acc[i][1] + bv.y;
        o.z = acc[i][2] + bv.z; o.w = acc[i][3] + bv.w;
        if (RELU) { o.x=fmaxf(o.x,0.f); o.y=fmaxf(o.y,0.f); o.z=fmaxf(o.z,0.f); o.w=fmaxf(o.w,0.f); }
        *(float4*)(Y + (size_t)(m0 + tm + i) * Nn + nc) = o;
    }
}

// ---------------------------------------------------------------------------
// bf16 MFMA Y = X @ W^T + bias (optional ReLU). X:(M,K) W:(N,K) bf16 (ushort),
// Y f32. Tile 128x128, BK=32, 256 thr = 4 waves, wave = 64x64 = 4x4 frags of
// mfma_f32_16x16x32_bf16. M%128==0, Nn%128==0, K%32==0. (Verified r10:
// op/pp/sk heads passed through this path.)
// ---------------------------------------------------------------------------
template<int RELU>
__global__ __launch_bounds__(256) void gemm_nt_mfma(
    const unsigned short* __restrict__ X, const unsigned short* __restrict__ W,
    const float* __restrict__ bias, float* __restrict__ Y, int K, int Nn)
{
    __shared__ unsigned short As[128][56];
    __shared__ unsigned short Bs[128][56];
    const int tid = threadIdx.x;
    const int m0 = blockIdx.y << 7;
    const int n0 = blockIdx.x << 7;
    const int wid = tid >> 6, lane = tid & 63;
    const int wm = (wid >> 1) << 6;
    const int wn = (wid & 1) << 6;
    const int sr = tid >> 2;
    const int sc = (tid & 3) << 3;

    f32x4 acc[4][4] = {};

    const int fr = lane & 15;
    const int kg = (lane >> 4) << 3;

    for (int k0 = 0; k0 < K; k0 += 32) {
        uint4 a0 = *(const uint4*)(X + (size_t)(m0 + sr) * K + k0 + sc);
        uint4 a1 = *(const uint4*)(X + (size_t)(m0 + sr + 64) * K + k0 + sc);
        uint4 b0 = *(const uint4*)(W + (size_t)(n0 + sr) * K + k0 + sc);
        uint4 b1 = *(const uint4*)(W + (size_t)(n0 + sr + 64) * K + k0 + sc);
        __syncthreads();
        *(uint4*)&As[sr][sc] = a0; *(uint4*)&As[sr + 64][sc] = a1;
        *(uint4*)&Bs[sr][sc] = b0; *(uint4*)&Bs[sr + 64][sc] = b1;
        __syncthreads();
        bf16x8 af[4], bf[4];
        #pragma unroll
        for (int i = 0; i < 4; ++i) {
            af[i] = *(const bf16x8*)&As[wm + i * 16 + fr][kg];
            bf[i] = *(const bf16x8*)&Bs[wn + i * 16 + fr][kg];
        }
        #pragma unroll
        for (int i = 0; i < 4; ++i)
            #pragma unroll
            for (int j = 0; j < 4; ++j)
                acc[i][j] = __builtin_amdgcn_mfma_f32_16x16x32_bf16(af[i], bf[j], acc[i][j], 0, 0, 0);
    }

    const int cr = (lane >> 4) << 2;
    const int cc = lane & 15;
    #pragma unroll
    for (int i = 0; i < 4; ++i) {
        #pragma unroll
        for (int j = 0; j < 4; ++j) {
            const int col = n0 + wn + j * 16 + cc;
            const float bv = bias ? bias[col] : 0.f;
            #pragma unroll
            for (int r = 0; r < 4; ++r) {
                const int row = m0 + wm + i * 16 + cr + r;
                float v = acc[i][j][r] + bv;
                if (RELU) v = fmaxf(v, 0.f);
                Y[(size_t)row * Nn + col] = v;
            }
        }
    }
}

// ---------------------------------------------------------------------------
// Batched Y[b] = (A[b] @ H[b]) * mask[b,:,None], optional ReLU (fp32).
// ---------------------------------------------------------------------------
template<int RELU>
__global__ __launch_bounds__(256) void gemm_nn_mask(const float* __restrict__ A,
    const float* __restrict__ Hm, const float* __restrict__ mask,
    float* __restrict__ Y, int M, int K, int Nn)
{
    const int b = blockIdx.z;
    A  += (size_t)b * M * K;
    Hm += (size_t)b * K * Nn;
    Y  += (size_t)b * M * Nn;
    __shared__ float As[16][68];
    __shared__ float Hs[16][68];
    const int tid = threadIdx.x;
    const int m0 = blockIdx.y << 6;
    const int n0 = blockIdx.x << 6;
    const int lr = tid >> 2;
    const int lc = (tid & 3) << 2;
    const int hr = tid >> 4;
    const int hc = (tid & 15) << 2;
    const int tm = (tid >> 4) << 2;
    const int tn = (tid & 15) << 2;

    float acc[4][4] = {{0.f,0.f,0.f,0.f},{0.f,0.f,0.f,0.f},{0.f,0.f,0.f,0.f},{0.f,0.f,0.f,0.f}};

    for (int k0 = 0; k0 < K; k0 += 16) {
        float4 av = *(const float4*)(A + (size_t)(m0 + lr) * K + k0 + lc);
        float4 hv = *(const float4*)(Hm + (size_t)(k0 + hr) * Nn + n0 + hc);
        __syncthreads();
        As[lc+0][lr]=av.x; As[lc+1][lr]=av.y; As[lc+2][lr]=av.z; As[lc+3][lr]=av.w;
        *(float4*)(&Hs[hr][hc]) = hv;
        __syncthreads();
        #pragma unroll
        for (int kk = 0; kk < 16; ++kk) {
            const float4 a = *(const float4*)(&As[kk][tm]);
            const float4 h = *(const float4*)(&Hs[kk][tn]);
            acc[0][0] += a.x*h.x; acc[0][1] += a.x*h.y; acc[0][2] += a.x*h.z; acc[0][3] += a.x*h.w;
            acc[1][0] += a.y*h.x; acc[1][1] += a.y*h.y; acc[1][2] += a.y*h.z; acc[1][3] += a.y*h.w;
            acc[2][0] += a.z*h.x; acc[2][1] += a.z*h.y; acc[2][2] += a.z*h.z; acc[2][3] += a.z*h.w;
            acc[3][0] += a.w*h.x; acc[3][1] += a.w*h.y; acc[3][2] += a.w*h.z; acc[3][3] += a.w*h.w;
        }
    }
    #pragma unroll
    for (int i = 0; i < 4; ++i) {
        const float mk = mask[b * M + m0 + tm + i];
        float4 o;
        o.x = acc[i][0]*mk; o.y = acc[i][1]*mk; o.z = acc[i][2]*mk; o.w = acc[i][3]*mk;
        if (RELU) { o.x=fmaxf(o.x,0.f); o.y=fmaxf(o.y,0.f); o.z=fmaxf(o.z,0.f); o.w=fmaxf(o.w,0.f); }
        *(float4*)(Y + (size_t)(m0 + tm + i) * Nn + n0 + tn) = o;
    }
}

// ---------------------------------------------------------------------------
__global__ __launch_bounds__(256) void attn_sisj(const float* __restrict__ h,
    const float* __restrict__ aw, const float* __restrict__ ab,
    float* __restrict__ si, float* __restrict__ sj)
{
    const int lane = threadIdx.x & 63;
    const int row  = (blockIdx.x << 2) + (threadIdx.x >> 6);
    const float4 hv = ((const float4*)(h + (size_t)row * HDIM))[lane];
    const float4 a1 = ((const float4*)aw)[lane];
    const float4 a2 = ((const float4*)(aw + HDIM))[lane];
    float s1 = hv.x*a1.x + hv.y*a1.y + hv.z*a1.z + hv.w*a1.w;
    float s2 = hv.x*a2.x + hv.y*a2.y + hv.z*a2.z + hv.w*a2.w;
    #pragma unroll
    for (int off = 32; off > 0; off >>= 1) {
        s1 += __shfl_down(s1, off);
        s2 += __shfl_down(s2, off);
    }
    if (lane == 0) { si[row] = s1 + ab[0]; sj[row] = s2; }
}

// ---------------------------------------------------------------------------
__global__ __launch_bounds__(512) void attn_score(const float* __restrict__ si,
    const float* __restrict__ sj, const float* __restrict__ adj,
    const float* __restrict__ mask, float* __restrict__ watt)
{
    const int bi = blockIdx.x;
    const int b  = bi >> 9;
    const int j  = threadIdx.x;
    const float s0 = si[bi];
    const float mi = mask[bi];
    float s = sigmoidf_(s0 + sj[(b << 9) + j]) * adj[(size_t)bi * NN + j] * mi * mask[(b << 9) + j];
    float t = s;
    #pragma unroll
    for (int off = 32; off > 0; off >>= 1) t += __shfl_down(t, off);
    __shared__ float red[8];
    const int lane = j & 63, wv = j >> 6;
    if (lane == 0) red[wv] = t;
    __syncthreads();
    if (j == 0) {
        float tot = 0.f;
        #pragma unroll
        for (int w = 0; w < 8; ++w) tot += red[w];
        red[0] = 1.0f / (tot + 1e-8f);
    }
    __syncthreads();
    watt[(size_t)bi * NN + j] = s * red[0];
}

// ---------------------------------------------------------------------------
// Pack fp32 -> f16x2 (u32) for the LSTM scan weights. n = element pairs.
// ---------------------------------------------------------------------------
__global__ __launch_bounds__(256) void pack_f16(const float* __restrict__ src,
    unsigned int* __restrict__ dst, int n)
{
    int i = blockIdx.x * 256 + threadIdx.x;
    if (i < n) {
        float2 v = ((const float2*)src)[i];
        _Float16 a = (_Float16)v.x, b = (_Float16)v.y;
        unsigned short ua = *(unsigned short*)&a, ub = *(unsigned short*)&b;
        dst[i] = (unsigned int)ua | ((unsigned int)ub << 16);
    }
}

// ---------------------------------------------------------------------------
// Pack up to 3 fp32 arrays -> bf16 (RNE). 4 elems/thread; all n % 4 == 0.
// ---------------------------------------------------------------------------
__global__ __launch_bounds__(256) void pack3_bf16(
    const float* __restrict__ s0, unsigned short* __restrict__ d0, int n0,
    const float* __restrict__ s1, unsigned short* __restrict__ d1, int n1,
    const float* __restrict__ s2, unsigned short* __restrict__ d2, int n2)
{
    int i = (blockIdx.x * 256 + threadIdx.x) * 4;
    const float* s; unsigned short* d; int l;
    if (i < n0) { s = s0; d = d0; l = i; }
    else if (i < n0 + n1) { s = s1; d = d1; l = i - n0; }
    else if (i < n0 + n1 + n2) { s = s2; d = d2; l = i - n0 - n1; }
    else return;
    float4 v = *(const float4*)(s + l);
    ushort4 o;
    o.x = f2bf_(v.x); o.y = f2bf_(v.y); o.z = f2bf_(v.z); o.w = f2bf_(v.w);
    *(ushort4*)(d + l) = o;
}

// ---------------------------------------------------------------------------
// Single-block-per-chain LSTM scan (r9 config, frozen — best measured:
// 985 us/dispatch = per-CU L2-BW floor for streamed weights).
// ---------------------------------------------------------------------------
__global__ __launch_bounds__(1024) __attribute__((amdgpu_waves_per_eu(4, 4)))
void lstm_scan7(
    const float* __restrict__ pre_f, const float* __restrict__ pre_b,
    const unsigned int* __restrict__ w16_f, const unsigned int* __restrict__ w16_b,
    float* __restrict__ out)
{
    __shared__ uint4v lw4[8 * 1024];
    __shared__ float g_s[1024];
    __shared__ unsigned int h2[128];

    const int chain = blockIdx.x;
    const int batch = chain >> 1;
    const int dir   = chain & 1;
    const float* pre = dir ? pre_b : pre_f;
    const unsigned int* w = dir ? w16_b : w16_f;
    const int t0 = threadIdx.x;

    const uint4v* wr = (const uint4v*)(w + (size_t)t0 * 128);

    #pragma unroll
    for (int i = 0; i < 8; ++i) lw4[i * 1024 + t0] = wr[24 + i];

#define WD(i) uint4v W##i = wr[i];
    WD(0) WD(1) WD(2) WD(3) WD(4) WD(5) WD(6) WD(7) WD(8) WD(9) WD(10) WD(11)
    WD(12) WD(13) WD(14) WD(15) WD(16) WD(17) WD(18) WD(19) WD(20) WD(21) WD(22) WD(23)
#undef WD
#define PIN_ALL \
    { \
        asm volatile("" : "+v"(W0)); asm volatile("" : "+v"(W1)); \
        asm volatile("" : "+v"(W2)); asm volatile("" : "+v"(W3)); \
        asm volatile("" : "+v"(W4)); asm volatile("" : "+v"(W5)); \
        asm volatile("" : "+v"(W6)); asm volatile("" : "+v"(W7)); \
        asm volatile("" : "+v"(W8)); asm volatile("" : "+v"(W9)); \
        asm volatile("" : "+v"(W10)); asm volatile("" : "+v"(W11)); \
        asm volatile("" : "+v"(W12)); asm volatile("" : "+v"(W13)); \
        asm volatile("" : "+v"(W14)); asm volatile("" : "+v"(W15)); \
        asm volatile("" : "+v"(W16)); asm volatile("" : "+v"(W17)); \
        asm volatile("" : "+v"(W18)); asm volatile("" : "+v"(W19)); \
        asm volatile("" : "+v"(W20)); asm volatile("" : "+v"(W21)); \
        asm volatile("" : "+v"(W22)); asm volatile("" : "+v"(W23)); \
    }
    PIN_ALL

    if (t0 < 128) h2[t0] = 0u;
    float c = 0.f;

    const int tt0 = dir ? (TT - 1) : 0;
    const long pstep = dir ? -1024 : 1024;
    const long ostep = dir ? -512 : 512;
    const float* pp = pre + ((size_t)batch * TT + tt0) * 1024 + t0;
    float* op = out + ((size_t)batch * TT + tt0) * 512 + dir * 256 + t0;
    float pv = *pp; pp += pstep;
    __syncthreads();

    for (int t = 0; t < TT; ++t) {
        PIN_ALL

        float pv_n = 0.f;
        if (t + 1 < TT) pv_n = *pp;
        pp += pstep;

        float a0 = 0.f, a1 = 0.f, a2 = 0.f, a3 = 0.f;
        const uint4v* h4 = (const uint4v*)h2;
#define DOT(i) { const uint4v hv = h4[i]; \
        a0 = fdot2_(W##i.x, hv.x, a0); a1 = fdot2_(W##i.y, hv.y, a1); \
        a2 = fdot2_(W##i.z, hv.z, a2); a3 = fdot2_(W##i.w, hv.w, a3); }
        DOT(0) DOT(1) DOT(2) DOT(3) DOT(4) DOT(5) DOT(6) DOT(7)
        DOT(8) DOT(9) DOT(10) DOT(11) DOT(12) DOT(13) DOT(14) DOT(15)
        DOT(16) DOT(17) DOT(18) DOT(19) DOT(20) DOT(21) DOT(22) DOT(23)
#undef DOT
        #pragma unroll
        for (int i = 0; i < 8; ++i) {
            const uint4v wv = lw4[i * 1024 + t0];
            const uint4v hv = h4[24 + i];
            a0 = fdot2_(wv.x, hv.x, a0); a1 = fdot2_(wv.y, hv.y, a1);
            a2 = fdot2_(wv.z, hv.z, a2); a3 = fdot2_(wv.w, hv.w, a3);
        }
        g_s[t0] = (a0 + a1) + (a2 + a3) + pv;
        __syncthreads();
        if (t0 < 256) {
            const float ig = sigmoidf_(g_s[t0]);
            const float fg = sigmoidf_(g_s[256 + t0]);
            const float gg = tanhf_(g_s[512 + t0]);
            const float og = sigmoidf_(g_s[768 + t0]);
            c = fg * c + ig * gg;
            const float h = og * tanhf_(c);
            *op = h;
            op += ostep;
            _Float16 hh = (_Float16)h;
            ((unsigned short*)h2)[t0] = *(unsigned short*)&hh;
        }
        pv = pv_n;
        __syncthreads();
    }
#undef PIN_ALL
}

// ---------------------------------------------------------------------------

extern "C" void kernel_launch(void* const* d_in, const int* in_sizes, int n_in,
                              void* d_out, int out_size, void* d_ws, size_t ws_size,
                              hipStream_t stream)
{
    const float* nf   = (const float*)d_in[0];
    const float* adj  = (const float*)d_in[1];
    const float* mask = (const float*)d_in[2];
    const float* g_w[3]  = {(const float*)d_in[4],  (const float*)d_in[8],  (const float*)d_in[12]};
    const float* g_b[3]  = {(const float*)d_in[5],  (const float*)d_in[9],  (const float*)d_in[13]};
    const float* g_aw[3] = {(const float*)d_in[6],  (const float*)d_in[10], (const float*)d_in[14]};
    const float* g_ab[3] = {(const float*)d_in[7],  (const float*)d_in[11], (const float*)d_in[15]};
    const float* wih0f = (const float*)d_in[16]; const float* whh0f = (const float*)d_in[17]; const float* b0f = (const float*)d_in[18];
    const float* wih0b = (const float*)d_in[19]; const float* whh0b = (const float*)d_in[20]; const float* b0b = (const float*)d_in[21];
    const float* wih1f = (const float*)d_in[22]; const float* whh1f = (const float*)d_in[23]; const float* b1f = (const float*)d_in[24];
    const float* wih1b = (const float*)d_in[25]; const float* whh1b = (const float*)d_in[26]; const float* b1b = (const float*)d_in[27];

    float* ws = (float*)d_ws;
    // Workspace layout (floats); total ~15.7M floats = ~63 MB (unchanged).
    float* bufA = ws;                       // (4096,256)
    float* bufB = bufA + 1048576;           // (4096,256); later f16 scan weights
    float* bufC = bufB + 1048576;           // (4096,256) GNN3 output
    float* si   = bufC + 1048576;           // (4096)
    float* sj   = si + 4096;                // (4096)
    float* out0 = sj + 4096;                // (4096,512)
    float* out1 = out0 + 2097152;           // (4096,512)
    float* P0   = out1 + 2097152;           // (4096,1024)
    float* P1   = P0 + 4194304;             // (4096,1024)
    float* watt = P0;                       // alias (GNN phase only)
    // f16 scan weights in bufB (dead after GNN3):
    unsigned int* w16_0f = (unsigned int*)bufB;
    unsigned int* w16_0b = w16_0f + 131072;
    unsigned int* w16_1f = w16_0b + 131072;
    unsigned int* w16_1b = w16_1f + 131072;
    // bf16 scratch, all aliased into phase-dead regions:
    // GNN phase (P1 free until proj0):
    unsigned short* nfp   = (unsigned short*)P1;                 // 524288 e
    unsigned short* bufBp = (unsigned short*)(P1 + 262144);      // 1048576 e
    unsigned short* gwp1  = (unsigned short*)(P1 + 786432);      // 32768 e
    unsigned short* gwp2  = (unsigned short*)(P1 + 802816);      // 65536 e
    unsigned short* gwp3  = (unsigned short*)(P1 + 835584);      // 65536 e
    // proj phase (bufA free; out1 free until scan1):
    unsigned short* bufCp  = (unsigned short*)bufA;              // 1048576 e
    unsigned short* out0p  = (unsigned short*)bufA;              // 2097152 e (after bufCp dead)
    unsigned short* wih0fp = (unsigned short*)out1;              // 262144 e
    unsigned short* wih0bp = (unsigned short*)(out1 + 131072);   // 262144 e
    unsigned short* wih1fp = (unsigned short*)(out1 + 262144);   // 524288 e
    unsigned short* wih1bp = (unsigned short*)(out1 + 524288);   // 524288 e
    // heads phase (P0/P1 free after scans).  r10 BUGFIX: bufC is (4096,256) =
    // 1,048,576 elements — bufCp2 was half-sized (524288), so the nd-head MFMA
    // read past it into unpacked garbage -> NaN. Full-size now; weights shifted.
    unsigned short* out1p  = (unsigned short*)P0;                // 2097152 e
    unsigned short* bufCp2 = (unsigned short*)(P0 + 1048576);    // 1048576 e
    unsigned short* opw1p  = (unsigned short*)(P0 + 1572864);    // 131072 e
    unsigned short* ppw1p  = (unsigned short*)(P0 + 1638400);    // 131072 e
    unsigned short* skw1p  = (unsigned short*)(P0 + 1703936);    // 131072 e
    unsigned short* ndw1p  = (unsigned short*)(P0 + 1769472);    // 65536 e

    const int MR = BB * NN;                 // 4096 rows
    dim3 blk(256);

    // ---------------- GNN x3 (projections via MFMA) ----------------
    pack3_bf16<<<dim3(608), blk, 0, stream>>>(nf, nfp, 524288,
                                              g_w[0], gwp1, 32768,
                                              g_w[1], gwp2, 65536);
    auto run_attn = [&](int li, float* ob, bool relu) {
        attn_sisj<<<dim3(MR / 4), blk, 0, stream>>>(bufA, g_aw[li], g_ab[li], si, sj);
        attn_score<<<dim3(MR), dim3(512), 0, stream>>>(si, sj, adj, mask, watt);
        if (relu)
            gemm_nn_mask<1><<<dim3(HDIM / 64, NN / 64, BB), blk, 0, stream>>>(watt, bufA, mask, ob, NN, NN, HDIM);
        else
            gemm_nn_mask<0><<<dim3(HDIM / 64, NN / 64, BB), blk, 0, stream>>>(watt, bufA, mask, ob, NN, NN, HDIM);
    };
    gemm_nt_mfma<0><<<dim3(2, 32), blk, 0, stream>>>(nfp, gwp1, g_b[0], bufA, NDIM, HDIM);
    run_attn(0, bufB, true);
    pack3_bf16<<<dim3(1088), blk, 0, stream>>>(bufB, bufBp, 1048576,
                                               g_w[2], gwp3, 65536,
                                               (const float*)0, (unsigned short*)0, 0);
    gemm_nt_mfma<0><<<dim3(2, 32), blk, 0, stream>>>(bufBp, gwp2, g_b[1], bufA, HDIM, HDIM);
    run_attn(1, bufB, true);
    pack3_bf16<<<dim3(1024), blk, 0, stream>>>(bufB, bufBp, 1048576,
                                               (const float*)0, (unsigned short*)0, 0,
                                               (const float*)0, (unsigned short*)0, 0);
    gemm_nt_mfma<0><<<dim3(2, 32), blk, 0, stream>>>(bufBp, gwp3, g_b[2], bufA, HDIM, HDIM);
    run_attn(2, bufC, false);

    // ---------------- pack scan whh weights to f16 (bufB now dead) ----------
    pack_f16<<<dim3(512), blk, 0, stream>>>(whh0f, w16_0f, 131072);
    pack_f16<<<dim3(512), blk, 0, stream>>>(whh0b, w16_0b, 131072);
    pack_f16<<<dim3(512), blk, 0, stream>>>(whh1f, w16_1f, 131072);
    pack_f16<<<dim3(512), blk, 0, stream>>>(whh1b, w16_1b, 131072);

    // ---------------- LSTM layer 0 ----------------
    pack3_bf16<<<dim3(1536), blk, 0, stream>>>(bufC, bufCp, 1048576,
                                               wih0f, wih0fp, 262144,
                                               wih0b, wih0bp, 262144);
    gemm_nt_mfma<0><<<dim3(8, 32), blk, 0, stream>>>(bufCp, wih0fp, b0f, P0, HDIM, 1024);
    gemm_nt_mfma<0><<<dim3(8, 32), blk, 0, stream>>>(bufCp, wih0bp, b0b, P1, HDIM, 1024);
    lstm_scan7<<<dim3(16), dim3(1024), 0, stream>>>(P0, P1, w16_0f, w16_0b, out0);

    // ---------------- LSTM layer 1 ----------------
    pack3_bf16<<<dim3(3072), blk, 0, stream>>>(out0, out0p, 2097152,
                                               wih1f, wih1fp, 524288,
                                               wih1b, wih1bp, 524288);
    gemm_nt_mfma<0><<<dim3(8, 32), blk, 0, stream>>>(out0p, wih1fp, b1f, P0, 512, 1024);
    gemm_nt_mfma<0><<<dim3(8, 32), blk, 0, stream>>>(out0p, wih1bp, b1b, P1, 512, 1024);
    lstm_scan7<<<dim3(16), dim3(1024), 0, stream>>>(P0, P1, w16_1f, w16_1b, out1);

    // ---------------- Heads ----------------
    float* out = (float*)d_out;
    pack3_bf16<<<dim3(3200), blk, 0, stream>>>(out1, out1p, 2097152,
                                               bufC, bufCp2, 1048576,
                                               (const float*)d_in[28], opw1p, 131072);
    pack3_bf16<<<dim3(320), blk, 0, stream>>>((const float*)d_in[32], ppw1p, 131072,
                                              (const float*)d_in[36], skw1p, 131072,
                                              (const float*)d_in[40], ndw1p, 65536);
    // op: (B,N,64) at offset 0
    gemm_nt_mfma<1><<<dim3(2, 32), blk, 0, stream>>>(out1p, opw1p, (const float*)d_in[29], bufA, 512, 256);
    gemm_nt<0><<<dim3(1, MR / 64), blk, 0, stream>>>(bufA, (const float*)d_in[30], (const float*)d_in[31], out, MR, 256, 64);
    // pp: (B,N,16) at offset 262144
    gemm_nt_mfma<1><<<dim3(2, 32), blk, 0, stream>>>(out1p, ppw1p, (const float*)d_in[33], bufA, 512, 256);
    gemm_nt<0><<<dim3(1, MR / 64), blk, 0, stream>>>(bufA, (const float*)d_in[34], (const float*)d_in[35], out + 262144, MR, 256, 16);
    // sk: (B,N,128) at offset 327680
    gemm_nt_mfma<1><<<dim3(2, 32), blk, 0, stream>>>(out1p, skw1p, (const float*)d_in[37], bufA, 512, 256);
    gemm_nt<0><<<dim3(2, MR / 64), blk, 0, stream>>>(bufA, (const float*)d_in[38], (const float*)d_in[39], out + 327680, MR, 256, 128);
    // nd: (B,N,128) at offset 851968 (input = GNN3 output)
    gemm_nt_mfma<1><<<dim3(2, 32), blk, 0, stream>>>(bufCp2, ndw1p, (const float*)d_in[41], bufA, 256, 256);
    gemm_nt<0><<<dim3(2, MR / 64), blk, 0, stream>>>(bufA, (const float*)d_in[42], (const float*)d_in[43], out + 851968, MR, 256, 128);
}